// Round 5
// baseline (123.164 us; speedup 1.0000x reference)
//
#include <hip/hip_runtime.h>

// ConditionalPreactivation: out = Z @ Wflat + bf @ bvec,
//   Z[b, k*512+i] = bf[b,k] * a[b,i],  a = lrelu(LN(x)),  bf = basis(c).
// GEMM: bf applied in-register to the A-fragment (f16 mul), BM=64 BN=128
// BK=32, 6 blocks/CU target, NSPLIT=8 -> grid 2048.  bvec folded in reduce.
// B=4096, DIN=512, DOUT=512, DC=64, K=16.

#define LRELU(v) ((v) >= 0.f ? (v) : 0.01f * (v))

typedef _Float16 f16x8 __attribute__((ext_vector_type(8)));
typedef float f32x4 __attribute__((ext_vector_type(4)));

#define GL16(gp, lp) __builtin_amdgcn_global_load_lds(                      \
    (const __attribute__((address_space(1))) void*)(gp),                    \
    (__attribute__((address_space(3))) void*)(lp), 16, 0, 0)

// ---------------------------------------------------------------------------
// Fused prep: blocks [0,256)      basis functions -> bf f32
//             blocks [256,1280)   W f32 -> Wt f16 transposed [o][k*512+i]
//             blocks [1280,2304)  LayerNorm+lrelu -> a f16
// ---------------------------------------------------------------------------
__global__ __launch_bounds__(256) void prep_kernel(
    const float* __restrict__ x, const float* __restrict__ gam,
    const float* __restrict__ bet, _Float16* __restrict__ a,
    const float* __restrict__ c, const float* __restrict__ w1,
    const float* __restrict__ b1, const float* __restrict__ wr,
    const float* __restrict__ br, const float* __restrict__ w2,
    const float* __restrict__ b2, float* __restrict__ bfo,
    const float* __restrict__ W, _Float16* __restrict__ Wt)
{
    __shared__ __align__(16) char smem[36864];
    int tid = threadIdx.x;
    int blk = blockIdx.x;

    if (blk < 256) {
        // ---------------- basis functions -> bf ----------------
        float* c_l  = (float*)smem;             // 16*64  = 4 KB
        float* lr_l = (float*)(smem + 4096);    // 16*256 = 16 KB
        float* h_l  = (float*)(smem + 20480);   // 16*256 = 16 KB
        int b0 = blk * 16;

        for (int i = tid; i < 16 * 64; i += 256) c_l[i] = c[(size_t)b0 * 64 + i];
        __syncthreads();

        float b1s = b1[tid];
        float h1[16];
#pragma unroll
        for (int r = 0; r < 16; ++r) h1[r] = b1s;

        for (int j4 = 0; j4 < 16; ++j4) {
            float wa = w1[(j4 * 4 + 0) * 256 + tid];
            float wb = w1[(j4 * 4 + 1) * 256 + tid];
            float wc = w1[(j4 * 4 + 2) * 256 + tid];
            float wd = w1[(j4 * 4 + 3) * 256 + tid];
#pragma unroll
            for (int r = 0; r < 16; ++r) {
                float4 cv = *(const float4*)&c_l[r * 64 + j4 * 4];
                h1[r] += cv.x * wa + cv.y * wb + cv.z * wc + cv.w * wd;
            }
        }
#pragma unroll
        for (int r = 0; r < 16; ++r) lr_l[r * 256 + tid] = LRELU(h1[r]);
        __syncthreads();

        float brv = br[tid];
        float h2[16];
#pragma unroll
        for (int r = 0; r < 16; ++r) h2[r] = h1[r] + brv;

        for (int j4 = 0; j4 < 64; ++j4) {
            float wa = wr[(j4 * 4 + 0) * 256 + tid];
            float wb = wr[(j4 * 4 + 1) * 256 + tid];
            float wc = wr[(j4 * 4 + 2) * 256 + tid];
            float wd = wr[(j4 * 4 + 3) * 256 + tid];
#pragma unroll
            for (int r = 0; r < 16; ++r) {
                float4 lv = *(const float4*)&lr_l[r * 256 + j4 * 4];
                h2[r] += lv.x * wa + lv.y * wb + lv.z * wc + lv.w * wd;
            }
        }
#pragma unroll
        for (int r = 0; r < 16; ++r) h_l[r * 256 + tid] = LRELU(h2[r]);
        __syncthreads();

        int r = tid >> 4, k = tid & 15;
        float s = b2[k];
        for (int q4 = 0; q4 < 64; ++q4) {
            float4 hv = *(const float4*)&h_l[r * 256 + q4 * 4];
            s += hv.x * w2[(q4 * 4 + 0) * 16 + k];
            s += hv.y * w2[(q4 * 4 + 1) * 16 + k];
            s += hv.z * w2[(q4 * 4 + 2) * 16 + k];
            s += hv.w * w2[(q4 * 4 + 3) * 16 + k];
        }
        bfo[(size_t)(b0 + r) * 16 + k] = s;

    } else if (blk < 1280) {
        // ---------------- W transpose + f16 convert ----------------
        float* t = (float*)smem;  // 64*65*4 = 16.25 KB
        int bid = blk - 256;
        int k  = bid >> 6;
        int it = (bid >> 3) & 7;
        int ot = bid & 7;
        int i0 = it * 64, o0 = ot * 64;

        int rr = tid >> 4, c4 = (tid & 15) * 4;
#pragma unroll
        for (int p = 0; p < 4; ++p) {
            int r = p * 16 + rr;
            float4 v = *(const float4*)&W[((size_t)(k * 512 + i0 + r)) * 512 + o0 + c4];
            t[r * 65 + c4 + 0] = v.x;
            t[r * 65 + c4 + 1] = v.y;
            t[r * 65 + c4 + 2] = v.z;
            t[r * 65 + c4 + 3] = v.w;
        }
        __syncthreads();

        int ol = tid >> 2, c0 = (tid & 3) * 16;
        _Float16 hb[16] __attribute__((aligned(16)));
#pragma unroll
        for (int u = 0; u < 16; ++u) hb[u] = (_Float16)t[(c0 + u) * 65 + ol];
        _Float16* dst = &Wt[(size_t)(o0 + ol) * 8192 + k * 512 + i0 + c0];
        *(float4*)dst       = *(const float4*)&hb[0];
        *(float4*)(dst + 8) = *(const float4*)&hb[8];

    } else {
        // ---------------- LayerNorm + LeakyReLU ----------------
        int lane = tid & 63;
        int row  = (blk - 1280) * 4 + (tid >> 6);
        const float* xr = x + (size_t)row * 512 + lane * 8;
        float4 v0 = *(const float4*)xr;
        float4 v1 = *(const float4*)(xr + 4);

        float s = v0.x + v0.y + v0.z + v0.w + v1.x + v1.y + v1.z + v1.w;
#pragma unroll
        for (int m = 1; m < 64; m <<= 1) s += __shfl_xor(s, m);
        float mean = s * (1.f / 512.f);

        float d, s2 = 0.f;
        d = v0.x - mean; s2 += d * d;
        d = v0.y - mean; s2 += d * d;
        d = v0.z - mean; s2 += d * d;
        d = v0.w - mean; s2 += d * d;
        d = v1.x - mean; s2 += d * d;
        d = v1.y - mean; s2 += d * d;
        d = v1.z - mean; s2 += d * d;
        d = v1.w - mean; s2 += d * d;
#pragma unroll
        for (int m = 1; m < 64; m <<= 1) s2 += __shfl_xor(s2, m);
        float rstd = rsqrtf(s2 * (1.f / 512.f) + 1e-5f);

        float4 g0 = *(const float4*)&gam[lane * 8];
        float4 g1 = *(const float4*)&gam[lane * 8 + 4];
        float4 b0 = *(const float4*)&bet[lane * 8];
        float4 b1v = *(const float4*)&bet[lane * 8 + 4];

        _Float16 o8[8] __attribute__((aligned(16)));
        float y;
        y = (v0.x - mean) * rstd * g0.x + b0.x;  y = LRELU(y); o8[0] = (_Float16)y;
        y = (v0.y - mean) * rstd * g0.y + b0.y;  y = LRELU(y); o8[1] = (_Float16)y;
        y = (v0.z - mean) * rstd * g0.z + b0.z;  y = LRELU(y); o8[2] = (_Float16)y;
        y = (v0.w - mean) * rstd * g0.w + b0.w;  y = LRELU(y); o8[3] = (_Float16)y;
        y = (v1.x - mean) * rstd * g1.x + b1v.x; y = LRELU(y); o8[4] = (_Float16)y;
        y = (v1.y - mean) * rstd * g1.y + b1v.y; y = LRELU(y); o8[5] = (_Float16)y;
        y = (v1.z - mean) * rstd * g1.z + b1v.z; y = LRELU(y); o8[6] = (_Float16)y;
        y = (v1.w - mean) * rstd * g1.w + b1v.w; y = LRELU(y); o8[7] = (_Float16)y;

        *(float4*)&a[(size_t)row * 512 + lane * 8] = *(const float4*)o8;
    }
}

// ---------------------------------------------------------------------------
// Main GEMM: partial[split][b,o] = sum_{kt in split} ((bf[:,kt]*a) @ W[kt])[b,o]
// BM=64, BN=128, BK=32, 4 waves (2x2: wm over 32-row halves, wn over 64-col
// halves), 16x16x32 f16 MFMA.  bf applied in-register on the A-fragment
// (row-pure per lane: row = l16).  High-occupancy: 12KB LDS, 6 waves/EU.
// grid = 64 * 4 * NSPLIT;  bid = m*(4*NSPLIT) + n*NSPLIT + split
// (split == bid % NSPLIT -> each XCD keeps its 1MB B-slice L2-resident)
// ---------------------------------------------------------------------------
template <int NSPLIT>
__global__ __launch_bounds__(256, 6) void gemm_kernel(
    const _Float16* __restrict__ A,   // [4096][512]
    const _Float16* __restrict__ Wt,  // [512][8192]
    const float* __restrict__ bfg,    // [4096][16]
    float* __restrict__ pout)         // [NSPLIT][4096][512]
{
    constexpr int KTN = 16 / NSPLIT;
    constexpr int PER = 4 * NSPLIT;

    __shared__ _Float16 As[64 * 32];   // 4 KB
    __shared__ _Float16 Bs[128 * 32];  // 8 KB

    int tid = threadIdx.x;
    int bid = blockIdx.x;
    int m     = bid / PER;
    int cc    = bid % PER;
    int n     = cc / NSPLIT;
    int split = cc % NSPLIT;
    int bm0 = m * 64, n0 = n * 128, kt0 = split * KTN;

    int lane = tid & 63, wid = tid >> 6;
    int wm = wid >> 1, wn = wid & 1;
    int l16 = lane & 15, lg = lane >> 4;

    // per-lane A-row scales (A-fragment row = l16), converted once to f16
    _Float16 s16[KTN][2];
#pragma unroll
    for (int kt = 0; kt < KTN; ++kt)
#pragma unroll
        for (int mi = 0; mi < 2; ++mi)
            s16[kt][mi] =
                (_Float16)bfg[(size_t)(bm0 + wm * 32 + mi * 16 + l16) * 16 + kt0 + kt];

    const f32x4 z4 = {0.f, 0.f, 0.f, 0.f};
    f32x4 acc[2][4];
#pragma unroll
    for (int mi = 0; mi < 2; ++mi)
#pragma unroll
        for (int ni = 0; ni < 4; ++ni) acc[mi][ni] = z4;

    // staging: A 64x32 (1 GL16/thread), B 128x32 (2 GL16/thread)
    int rr = tid >> 2, c8 = (tid & 3) * 8;
    const _Float16* asrc  = A  + (size_t)(bm0 + rr) * 512 + c8;
    const _Float16* bsrc  = Wt + (size_t)(n0 + rr) * 8192 + c8;
    const _Float16* bsrc1 = bsrc + (size_t)64 * 8192;
    char* asl  = (char*)As + tid * 16;
    char* bsl0 = (char*)Bs + tid * 16;
    char* bsl1 = (char*)Bs + (256 + tid) * 16;

    // LDS read offsets (fixed)
    const _Float16* arp = &As[(wm * 32 + l16) * 32 + lg * 8];
    const _Float16* brp = &Bs[(wn * 64 + l16) * 32 + lg * 8];

#pragma unroll 1
    for (int kt = 0; kt < KTN; ++kt) {
        size_t koff = (size_t)(kt0 + kt) * 512;
        _Float16 s0 = s16[kt][0], s1 = s16[kt][1];
#pragma unroll 1
        for (int ks = 0; ks < 16; ++ks) {
            int ig = ks * 32;
            GL16(asrc + ig, asl);
            GL16(bsrc + koff + ig, bsl0);
            GL16(bsrc1 + koff + ig, bsl1);
            __syncthreads();

            f16x8 a0 = *(const f16x8*)arp;
            f16x8 a1 = *(const f16x8*)(arp + 16 * 32);
            f16x8 b0 = *(const f16x8*)brp;
            f16x8 b1 = *(const f16x8*)(brp + 16 * 32);
            f16x8 b2 = *(const f16x8*)(brp + 32 * 32);
            f16x8 b3 = *(const f16x8*)(brp + 48 * 32);

            f16x8 as0 = a0 * s0;
            f16x8 as1 = a1 * s1;

            acc[0][0] = __builtin_amdgcn_mfma_f32_16x16x32_f16(as0, b0, acc[0][0], 0, 0, 0);
            acc[0][1] = __builtin_amdgcn_mfma_f32_16x16x32_f16(as0, b1, acc[0][1], 0, 0, 0);
            acc[0][2] = __builtin_amdgcn_mfma_f32_16x16x32_f16(as0, b2, acc[0][2], 0, 0, 0);
            acc[0][3] = __builtin_amdgcn_mfma_f32_16x16x32_f16(as0, b3, acc[0][3], 0, 0, 0);
            acc[1][0] = __builtin_amdgcn_mfma_f32_16x16x32_f16(as1, b0, acc[1][0], 0, 0, 0);
            acc[1][1] = __builtin_amdgcn_mfma_f32_16x16x32_f16(as1, b1, acc[1][1], 0, 0, 0);
            acc[1][2] = __builtin_amdgcn_mfma_f32_16x16x32_f16(as1, b2, acc[1][2], 0, 0, 0);
            acc[1][3] = __builtin_amdgcn_mfma_f32_16x16x32_f16(as1, b3, acc[1][3], 0, 0, 0);
            __syncthreads();
        }
    }

    float* op = pout + (size_t)split * (4096 * 512);
#pragma unroll
    for (int mi = 0; mi < 2; ++mi)
#pragma unroll
        for (int j = 0; j < 4; ++j) {
            int grow = bm0 + wm * 32 + mi * 16 + lg * 4 + j;
#pragma unroll
            for (int ni = 0; ni < 4; ++ni) {
                int col = n0 + wn * 64 + ni * 16 + l16;
                op[(size_t)grow * 512 + col] = acc[mi][ni][j];
            }
        }
}

// ---------------------------------------------------------------------------
// out = sum over splits of partials + bf @ bvec.  One float4 per thread.
// ---------------------------------------------------------------------------
__global__ __launch_bounds__(256) void reduce_kernel(const float* __restrict__ p,
                                                     const float* __restrict__ bfg,
                                                     const float* __restrict__ bvec,
                                                     float* __restrict__ out,
                                                     int nsplit)
{
    size_t i = (size_t)blockIdx.x * 256 + threadIdx.x;  // float4 index
    const float4* p4 = (const float4*)p;
    float4 s = p4[i];
    for (int sp = 1; sp < nsplit; ++sp) {
        float4 v = p4[i + (size_t)sp * 524288];
        s.x += v.x; s.y += v.y; s.z += v.z; s.w += v.w;
    }
    int b = (int)(i >> 7);        // 128 float4 per row
    int c = (int)(i & 127);
    const float* bfr = bfg + (size_t)b * 16;
    const float4* bv4 = (const float4*)bvec;  // [16][128] float4
#pragma unroll
    for (int k = 0; k < 16; ++k) {
        float bk = bfr[k];
        float4 v = bv4[k * 128 + c];
        s.x += bk * v.x; s.y += bk * v.y; s.z += bk * v.z; s.w += bk * v.w;
    }
    ((float4*)out)[i] = s;
}

// ---------------------------------------------------------------------------
extern "C" void kernel_launch(void* const* d_in, const int* in_sizes, int n_in,
                              void* d_out, int out_size, void* d_ws, size_t ws_size,
                              hipStream_t stream)
{
    const float* x    = (const float*)d_in[0];
    const float* c    = (const float*)d_in[1];
    const float* gam  = (const float*)d_in[2];
    const float* bet  = (const float*)d_in[3];
    const float* w1   = (const float*)d_in[4];
    const float* b1   = (const float*)d_in[5];
    const float* wr   = (const float*)d_in[6];
    const float* br   = (const float*)d_in[7];
    const float* w2   = (const float*)d_in[8];
    const float* b2   = (const float*)d_in[9];
    const float* W    = (const float*)d_in[10];
    const float* bvec = (const float*)d_in[11];
    float* out = (float*)d_out;

    const size_t outBytes  = (size_t)4096 * 512 * 4;                  // 8 MB
    const size_t miscBytes = (8u << 20) + (4u << 20) + (256u << 10);  // Wt+a+bf

    // nsplit=8 needs 76.25 MB of ws (selected successfully in round 4).
    int nsplit = (ws_size >= 8 * outBytes + miscBytes) ? 8 : 4;

    char* ws = (char*)d_ws;
    size_t pbytes = (size_t)nsplit * outBytes;
    float*    part = (float*)ws;
    _Float16* Wt   = (_Float16*)(ws + pbytes);
    _Float16* af   = (_Float16*)(ws + pbytes + (8u << 20));
    float*    bf   = (float*)(ws + pbytes + (12u << 20));

    prep_kernel<<<dim3(2304), dim3(256), 0, stream>>>(
        x, gam, bet, af, c, w1, b1, wr, br, w2, b2, bf, W, Wt);

    if (nsplit == 8) {
        // 64 m-tiles * 4 n-tiles * 8 splits = 2048 blocks (8/CU queued, 6 resident)
        gemm_kernel<8><<<dim3(2048), dim3(256), 0, stream>>>(af, Wt, bf, part);
    } else {
        // 64 m-tiles * 4 n-tiles * 4 splits = 1024 blocks
        gemm_kernel<4><<<dim3(1024), dim3(256), 0, stream>>>(af, Wt, bf, part);
    }
    reduce_kernel<<<dim3(2048), dim3(256), 0, stream>>>(part, bf, bvec, out, nsplit);
}

// Round 6
// 98.843 us; speedup vs baseline: 1.2461x; 1.2461x over previous
//
#include <hip/hip_runtime.h>

// ConditionalPreactivation: out = Z @ Wflat + bf @ bvec,
//   Z[b, k*512+i] = bf[b,k] * a[b,i],  a = lrelu(LN(x)),  bf = basis(c).
// 256x256 deep-pipelined GEMM (counted vmcnt, 2-deep LDS double buffer,
// T2 read-swizzle, T5 setprio), bf applied in-register on A-fragments.
// Split-K=8 -> grid 256 (1 block/CU).  bvec folded in reduce.
// B=4096, DIN=512, DOUT=512, DC=64, K=16, DB=256.

#define LRELU(v) ((v) >= 0.f ? (v) : 0.01f * (v))

typedef _Float16 f16x8 __attribute__((ext_vector_type(8)));
typedef float f32x4 __attribute__((ext_vector_type(4)));

#define GL16(gp, lp) __builtin_amdgcn_global_load_lds(                      \
    (const __attribute__((address_space(1))) void*)(gp),                    \
    (__attribute__((address_space(3))) void*)(lp), 16, 0, 0)

#define MFMA16(a, b, c) __builtin_amdgcn_mfma_f32_16x16x32_f16((a), (b), (c), 0, 0, 0)

// ---------------------------------------------------------------------------
// Fused prep: blocks [0,256)      basis functions -> bf f32
//             blocks [256,1280)   W f32 -> Wt f16 transposed [o][k*512+i]
//             blocks [1280,2304)  LayerNorm+lrelu -> a f16
// ---------------------------------------------------------------------------
__global__ __launch_bounds__(256) void prep_kernel(
    const float* __restrict__ x, const float* __restrict__ gam,
    const float* __restrict__ bet, _Float16* __restrict__ a,
    const float* __restrict__ c, const float* __restrict__ w1,
    const float* __restrict__ b1, const float* __restrict__ wr,
    const float* __restrict__ br, const float* __restrict__ w2,
    const float* __restrict__ b2, float* __restrict__ bfo,
    const float* __restrict__ W, _Float16* __restrict__ Wt)
{
    __shared__ __align__(16) char smem[36864];
    int tid = threadIdx.x;
    int blk = blockIdx.x;

    if (blk < 256) {
        // ---------------- basis functions -> bf ----------------
        float* c_l  = (float*)smem;             // 16*64  = 4 KB
        float* lr_l = (float*)(smem + 4096);    // 16*256 = 16 KB
        float* h_l  = (float*)(smem + 20480);   // 16*256 = 16 KB
        int b0 = blk * 16;

        for (int i = tid; i < 16 * 64; i += 256) c_l[i] = c[(size_t)b0 * 64 + i];
        __syncthreads();

        float b1s = b1[tid];
        float h1[16];
#pragma unroll
        for (int r = 0; r < 16; ++r) h1[r] = b1s;

        for (int j4 = 0; j4 < 16; ++j4) {
            float wa = w1[(j4 * 4 + 0) * 256 + tid];
            float wb = w1[(j4 * 4 + 1) * 256 + tid];
            float wc = w1[(j4 * 4 + 2) * 256 + tid];
            float wd = w1[(j4 * 4 + 3) * 256 + tid];
#pragma unroll
            for (int r = 0; r < 16; ++r) {
                float4 cv = *(const float4*)&c_l[r * 64 + j4 * 4];
                h1[r] += cv.x * wa + cv.y * wb + cv.z * wc + cv.w * wd;
            }
        }
#pragma unroll
        for (int r = 0; r < 16; ++r) lr_l[r * 256 + tid] = LRELU(h1[r]);
        __syncthreads();

        float brv = br[tid];
        float h2[16];
#pragma unroll
        for (int r = 0; r < 16; ++r) h2[r] = h1[r] + brv;

        for (int j4 = 0; j4 < 64; ++j4) {
            float wa = wr[(j4 * 4 + 0) * 256 + tid];
            float wb = wr[(j4 * 4 + 1) * 256 + tid];
            float wc = wr[(j4 * 4 + 2) * 256 + tid];
            float wd = wr[(j4 * 4 + 3) * 256 + tid];
#pragma unroll
            for (int r = 0; r < 16; ++r) {
                float4 lv = *(const float4*)&lr_l[r * 256 + j4 * 4];
                h2[r] += lv.x * wa + lv.y * wb + lv.z * wc + lv.w * wd;
            }
        }
#pragma unroll
        for (int r = 0; r < 16; ++r) h_l[r * 256 + tid] = LRELU(h2[r]);
        __syncthreads();

        int r = tid >> 4, k = tid & 15;
        float s = b2[k];
        for (int q4 = 0; q4 < 64; ++q4) {
            float4 hv = *(const float4*)&h_l[r * 256 + q4 * 4];
            s += hv.x * w2[(q4 * 4 + 0) * 16 + k];
            s += hv.y * w2[(q4 * 4 + 1) * 16 + k];
            s += hv.z * w2[(q4 * 4 + 2) * 16 + k];
            s += hv.w * w2[(q4 * 4 + 3) * 16 + k];
        }
        bfo[(size_t)(b0 + r) * 16 + k] = s;

    } else if (blk < 1280) {
        // ---------------- W transpose + f16 convert ----------------
        float* t = (float*)smem;  // 64*65*4 = 16.25 KB
        int bid = blk - 256;
        int k  = bid >> 6;
        int it = (bid >> 3) & 7;
        int ot = bid & 7;
        int i0 = it * 64, o0 = ot * 64;

        int rr = tid >> 4, c4 = (tid & 15) * 4;
#pragma unroll
        for (int p = 0; p < 4; ++p) {
            int r = p * 16 + rr;
            float4 v = *(const float4*)&W[((size_t)(k * 512 + i0 + r)) * 512 + o0 + c4];
            t[r * 65 + c4 + 0] = v.x;
            t[r * 65 + c4 + 1] = v.y;
            t[r * 65 + c4 + 2] = v.z;
            t[r * 65 + c4 + 3] = v.w;
        }
        __syncthreads();

        int ol = tid >> 2, c0 = (tid & 3) * 16;
        _Float16 hb[16] __attribute__((aligned(16)));
#pragma unroll
        for (int u = 0; u < 16; ++u) hb[u] = (_Float16)t[(c0 + u) * 65 + ol];
        _Float16* dst = &Wt[(size_t)(o0 + ol) * 8192 + k * 512 + i0 + c0];
        *(float4*)dst       = *(const float4*)&hb[0];
        *(float4*)(dst + 8) = *(const float4*)&hb[8];

    } else {
        // ---------------- LayerNorm + LeakyReLU ----------------
        int lane = tid & 63;
        int row  = (blk - 1280) * 4 + (tid >> 6);
        const float* xr = x + (size_t)row * 512 + lane * 8;
        float4 v0 = *(const float4*)xr;
        float4 v1 = *(const float4*)(xr + 4);

        float s = v0.x + v0.y + v0.z + v0.w + v1.x + v1.y + v1.z + v1.w;
#pragma unroll
        for (int m = 1; m < 64; m <<= 1) s += __shfl_xor(s, m);
        float mean = s * (1.f / 512.f);

        float d, s2 = 0.f;
        d = v0.x - mean; s2 += d * d;
        d = v0.y - mean; s2 += d * d;
        d = v0.z - mean; s2 += d * d;
        d = v0.w - mean; s2 += d * d;
        d = v1.x - mean; s2 += d * d;
        d = v1.y - mean; s2 += d * d;
        d = v1.z - mean; s2 += d * d;
        d = v1.w - mean; s2 += d * d;
#pragma unroll
        for (int m = 1; m < 64; m <<= 1) s2 += __shfl_xor(s2, m);
        float rstd = rsqrtf(s2 * (1.f / 512.f) + 1e-5f);

        float4 g0 = *(const float4*)&gam[lane * 8];
        float4 g1 = *(const float4*)&gam[lane * 8 + 4];
        float4 b0 = *(const float4*)&bet[lane * 8];
        float4 b1v = *(const float4*)&bet[lane * 8 + 4];

        _Float16 o8[8] __attribute__((aligned(16)));
        float y;
        y = (v0.x - mean) * rstd * g0.x + b0.x;  y = LRELU(y); o8[0] = (_Float16)y;
        y = (v0.y - mean) * rstd * g0.y + b0.y;  y = LRELU(y); o8[1] = (_Float16)y;
        y = (v0.z - mean) * rstd * g0.z + b0.z;  y = LRELU(y); o8[2] = (_Float16)y;
        y = (v0.w - mean) * rstd * g0.w + b0.w;  y = LRELU(y); o8[3] = (_Float16)y;
        y = (v1.x - mean) * rstd * g1.x + b1v.x; y = LRELU(y); o8[4] = (_Float16)y;
        y = (v1.y - mean) * rstd * g1.y + b1v.y; y = LRELU(y); o8[5] = (_Float16)y;
        y = (v1.z - mean) * rstd * g1.z + b1v.z; y = LRELU(y); o8[6] = (_Float16)y;
        y = (v1.w - mean) * rstd * g1.w + b1v.w; y = LRELU(y); o8[7] = (_Float16)y;

        *(float4*)&a[(size_t)row * 512 + lane * 8] = *(const float4*)o8;
    }
}

// ---------------------------------------------------------------------------
// Main GEMM: partial[split][b,o] = sum_{kt in split} ((bf[:,kt]*a) @ W[kt])[b,o]
// BM=BN=256, BK=64, 8 waves (2M x 4N), 512 threads, 16x16x32 f16 MFMA.
// 2-deep tile double buffer; counted vmcnt(8) (never 0 in steady state);
// raw s_barrier (no __syncthreads -> no vmcnt(0) drain); T2 xor-swizzle:
// linear GL16 dest + inverse-swizzled global source + swizzled ds_read;
// T5 setprio around each 16-MFMA quadrant.
// grid = 16m * 2n * NSPLIT; bid: split = bid % NSPLIT (XCD-contiguous).
// Pipeline invariants:
//   - before compute(t): buf[t&1] holds tile t (prologue / barrier#2 of t-1)
//   - barrier#1 after compute(t): all waves done reading buf[t&1]
//   - stage(t+2) -> buf[t&1]; vmcnt(8) waits t+1's 8 loads; barrier#2.
// ---------------------------------------------------------------------------
template <int NSPLIT>
__global__ __launch_bounds__(512, 2) void gemm_kernel(
    const _Float16* __restrict__ A,   // [4096][512]
    const _Float16* __restrict__ Wt,  // [512][8192]
    const float* __restrict__ bfg,    // [4096][16]
    float* __restrict__ pout)         // [NSPLIT][4096][512]
{
    constexpr int KTN = 16 / NSPLIT;   // kt-groups per block
    constexpr int NT  = KTN * 8;       // K-tiles of 64

    __shared__ _Float16 As[2][256 * 64];  // 64 KB
    __shared__ _Float16 Bs[2][256 * 64];  // 64 KB

    const int tid = threadIdx.x;
    const int bid = blockIdx.x;
    const int split = bid % NSPLIT;
    const int mn  = bid / NSPLIT;
    const int n0  = (mn & 1) * 256;
    const int bm0 = (mn >> 1) * 256;
    const int kt0 = split * KTN;

    const int lane = tid & 63, wid = tid >> 6;
    const int wm = wid >> 2, wn = wid & 3;   // 2 x 4 wave grid
    const int l16 = lane & 15, lg = lane >> 4;

    // per-lane A-row scales: row = bm0 + wm*128 + f*16 + l16
    _Float16 s16[KTN][8];
#pragma unroll
    for (int kt = 0; kt < KTN; ++kt)
#pragma unroll
        for (int f = 0; f < 8; ++f)
            s16[kt][f] = (_Float16)
                bfg[(size_t)(bm0 + wm * 128 + f * 16 + l16) * 16 + kt0 + kt];

    // ---- staging: tile = 256x64 f16 = 2048 16B-chunks; round p: chunk = p*512+tid
    // chunk -> (row = chunk>>3, c = chunk&7); source column chunk = c ^ (row&7)
    // (row&7 invariant across p since rows step by 64)
    const int brow = tid >> 3;
    const int bc   = tid & 7;
    const int swc  = bc ^ (brow & 7);
    const _Float16* aAs = A  + (size_t)(bm0 + brow) * 512  + swc * 8;
    const _Float16* aBs = Wt + (size_t)(n0  + brow) * 8192 + swc * 8;

    auto STAGE = [&](int t, int buf) {
        const int ka = (t & 7) * 64;                            // A col offset
        const size_t kb = (size_t)(kt0 + (t >> 3)) * 512 + ka;  // B col offset
        char* la = (char*)&As[buf][0] + tid * 16;
        char* lb = (char*)&Bs[buf][0] + tid * 16;
#pragma unroll
        for (int p = 0; p < 4; ++p) {
            GL16(aAs + (size_t)(p * 64) * 512 + ka, la + p * 8192);
            GL16(aBs + (size_t)(p * 64) * 8192 + kb, lb + p * 8192);
        }
    };

    // ---- swizzled ds_read offsets: logical byte = row*128 + (kk*4+lg)*16,
    // physical chunk = (kk*4+lg) ^ (row&7); row&7 == l16&7 for all our rows.
    const int swr = l16 & 7;
    const int aRowByte = (wm * 128 + l16) * 128;
    const int bRowByte = (wn * 64 + l16) * 128;
    const int sw0 = ((0 + lg) ^ swr) << 4;   // kk = 0
    const int sw1 = ((4 + lg) ^ swr) << 4;   // kk = 1

    const f32x4 z4 = {0.f, 0.f, 0.f, 0.f};
    f32x4 acc[8][4];
#pragma unroll
    for (int f = 0; f < 8; ++f)
#pragma unroll
        for (int nf = 0; nf < 4; ++nf) acc[f][nf] = z4;

    // ---- prologue: stage tiles 0,1; wait tile 0 (8 of 16 outstanding)
    STAGE(0, 0);
    STAGE(1, 1);
    asm volatile("s_waitcnt vmcnt(8)" ::: "memory");
    __builtin_amdgcn_s_barrier();
    __builtin_amdgcn_sched_barrier(0);

#pragma unroll
    for (int kt = 0; kt < KTN; ++kt) {
#pragma unroll 1
        for (int t2 = 0; t2 < 8; ++t2) {
            const int t = kt * 8 + t2;
            const int cur = t & 1;
            const char* Ab = (const char*)&As[cur][0];
            const char* Bb = (const char*)&Bs[cur][0];

            // B fragments for the whole K-tile (8 x ds_read_b128)
            f16x8 b8[4][2];
#pragma unroll
            for (int nf = 0; nf < 4; ++nf) {
                b8[nf][0] = *(const f16x8*)(Bb + bRowByte + nf * 2048 + sw0);
                b8[nf][1] = *(const f16x8*)(Bb + bRowByte + nf * 2048 + sw1);
            }

            // 4 quadrants: 4 A-reads + scale + 16 MFMA each
#pragma unroll
            for (int q = 0; q < 4; ++q) {
                f16x8 a0k0 = *(const f16x8*)(Ab + aRowByte + (2 * q + 0) * 2048 + sw0);
                f16x8 a0k1 = *(const f16x8*)(Ab + aRowByte + (2 * q + 0) * 2048 + sw1);
                f16x8 a1k0 = *(const f16x8*)(Ab + aRowByte + (2 * q + 1) * 2048 + sw0);
                f16x8 a1k1 = *(const f16x8*)(Ab + aRowByte + (2 * q + 1) * 2048 + sw1);
                const _Float16 sc0 = s16[kt][2 * q + 0];
                const _Float16 sc1 = s16[kt][2 * q + 1];
                a0k0 *= sc0; a0k1 *= sc0;
                a1k0 *= sc1; a1k1 *= sc1;
                __builtin_amdgcn_s_setprio(1);
#pragma unroll
                for (int nf = 0; nf < 4; ++nf) {
                    acc[2 * q + 0][nf] = MFMA16(a0k0, b8[nf][0], acc[2 * q + 0][nf]);
                    acc[2 * q + 0][nf] = MFMA16(a0k1, b8[nf][1], acc[2 * q + 0][nf]);
                    acc[2 * q + 1][nf] = MFMA16(a1k0, b8[nf][0], acc[2 * q + 1][nf]);
                    acc[2 * q + 1][nf] = MFMA16(a1k1, b8[nf][1], acc[2 * q + 1][nf]);
                }
                __builtin_amdgcn_s_setprio(0);
            }

            // barrier#1: all waves done reading buf[cur]
            __builtin_amdgcn_sched_barrier(0);
            __builtin_amdgcn_s_barrier();
            __builtin_amdgcn_sched_barrier(0);

            if (t + 2 < NT) {
                STAGE(t + 2, cur);                      // overwrite buf[cur]
                asm volatile("s_waitcnt vmcnt(8)" ::: "memory");  // tile t+1 landed
            } else {
                asm volatile("s_waitcnt vmcnt(0)" ::: "memory");
            }
            // barrier#2: buf[cur^1] (tile t+1) ready for every wave
            __builtin_amdgcn_s_barrier();
            __builtin_amdgcn_sched_barrier(0);
        }
    }

    // ---- epilogue: plain stores to this split's partial buffer
    float* op = pout + (size_t)split * (4096 * 512);
#pragma unroll
    for (int f = 0; f < 8; ++f)
#pragma unroll
        for (int j = 0; j < 4; ++j) {
            const int grow = bm0 + wm * 128 + f * 16 + lg * 4 + j;
            float* orow = op + (size_t)grow * 512 + n0 + wn * 64 + l16;
#pragma unroll
            for (int nf = 0; nf < 4; ++nf)
                orow[nf * 16] = acc[f][nf][j];
        }
}

// ---------------------------------------------------------------------------
// out = sum over splits of partials + bf @ bvec.  One float4 per thread.
// ---------------------------------------------------------------------------
__global__ __launch_bounds__(256) void reduce_kernel(const float* __restrict__ p,
                                                     const float* __restrict__ bfg,
                                                     const float* __restrict__ bvec,
                                                     float* __restrict__ out,
                                                     int nsplit)
{
    size_t i = (size_t)blockIdx.x * 256 + threadIdx.x;  // float4 index
    const float4* p4 = (const float4*)p;
    float4 s = p4[i];
    for (int sp = 1; sp < nsplit; ++sp) {
        float4 v = p4[i + (size_t)sp * 524288];
        s.x += v.x; s.y += v.y; s.z += v.z; s.w += v.w;
    }
    int b = (int)(i >> 7);        // 128 float4 per row
    int c = (int)(i & 127);
    const float* bfr = bfg + (size_t)b * 16;
    const float4* bv4 = (const float4*)bvec;  // [16][128] float4
#pragma unroll
    for (int k = 0; k < 16; ++k) {
        float bk = bfr[k];
        float4 v = bv4[k * 128 + c];
        s.x += bk * v.x; s.y += bk * v.y; s.z += bk * v.z; s.w += bk * v.w;
    }
    ((float4*)out)[i] = s;
}

// ---------------------------------------------------------------------------
extern "C" void kernel_launch(void* const* d_in, const int* in_sizes, int n_in,
                              void* d_out, int out_size, void* d_ws, size_t ws_size,
                              hipStream_t stream)
{
    const float* x    = (const float*)d_in[0];
    const float* c    = (const float*)d_in[1];
    const float* gam  = (const float*)d_in[2];
    const float* bet  = (const float*)d_in[3];
    const float* w1   = (const float*)d_in[4];
    const float* b1   = (const float*)d_in[5];
    const float* wr   = (const float*)d_in[6];
    const float* br   = (const float*)d_in[7];
    const float* w2   = (const float*)d_in[8];
    const float* b2   = (const float*)d_in[9];
    const float* W    = (const float*)d_in[10];
    const float* bvec = (const float*)d_in[11];
    float* out = (float*)d_out;

    const size_t outBytes  = (size_t)4096 * 512 * 4;                  // 8 MB
    const size_t miscBytes = (8u << 20) + (4u << 20) + (256u << 10);  // Wt+a+bf

    // nsplit=8 needs 76.25 MB of ws (selected successfully rounds 4-5).
    int nsplit = (ws_size >= 8 * outBytes + miscBytes) ? 8 : 4;

    char* ws = (char*)d_ws;
    size_t pbytes = (size_t)nsplit * outBytes;
    float*    part = (float*)ws;
    _Float16* Wt   = (_Float16*)(ws + pbytes);
    _Float16* af   = (_Float16*)(ws + pbytes + (8u << 20));
    float*    bf   = (float*)(ws + pbytes + (12u << 20));

    prep_kernel<<<dim3(2304), dim3(256), 0, stream>>>(
        x, gam, bet, af, c, w1, b1, wr, br, w2, b2, bf, W, Wt);

    if (nsplit == 8) {
        // 16 m-tiles * 2 n-tiles * 8 splits = 256 blocks (1 per CU)
        gemm_kernel<8><<<dim3(256), dim3(512), 0, stream>>>(af, Wt, bf, part);
    } else {
        gemm_kernel<4><<<dim3(128), dim3(512), 0, stream>>>(af, Wt, bf, part);
    }
    reduce_kernel<<<dim3(2048), dim3(256), 0, stream>>>(part, bf, bvec, out, nsplit);
}

// Round 7
// 92.083 us; speedup vs baseline: 1.3375x; 1.0734x over previous
//
#include <hip/hip_runtime.h>

// ConditionalPreactivation: out = Z @ Wflat + bf @ bvec,
//   Z[b, k*512+i] = bf[b,k] * a[b,i],  a = lrelu(LN(x)),  bf = basis(c).
// 256x256 deep-pipelined GEMM (counted vmcnt, 2-deep LDS double buffer,
// T2 read-swizzle, T5 setprio), bf applied in-register on A-fragments.
// Split-K=8 -> grid 256 (1 block/CU).  bvec folded in reduce.
// Prep: latency-optimized (register-cached weights, chunked loads, 512
// bf-blocks x 8 rows, 18.4 KB LDS).
// B=4096, DIN=512, DOUT=512, DC=64, K=16, DB=256.

#define LRELU(v) ((v) >= 0.f ? (v) : 0.01f * (v))

typedef _Float16 f16x8 __attribute__((ext_vector_type(8)));
typedef float f32x4 __attribute__((ext_vector_type(4)));

#define GL16(gp, lp) __builtin_amdgcn_global_load_lds(                      \
    (const __attribute__((address_space(1))) void*)(gp),                    \
    (__attribute__((address_space(3))) void*)(lp), 16, 0, 0)

#define MFMA16(a, b, c) __builtin_amdgcn_mfma_f32_16x16x32_f16((a), (b), (c), 0, 0, 0)

// ---------------------------------------------------------------------------
// Fused prep: blocks [0,512)      basis functions -> bf f32  (8 rows/block)
//             blocks [512,1536)   W f32 -> Wt f16 transposed [o][k*512+i]
//             blocks [1536,2560)  LayerNorm+lrelu -> a f16
// ---------------------------------------------------------------------------
__global__ __launch_bounds__(256) void prep_kernel(
    const float* __restrict__ x, const float* __restrict__ gam,
    const float* __restrict__ bet, _Float16* __restrict__ a,
    const float* __restrict__ c, const float* __restrict__ w1,
    const float* __restrict__ b1, const float* __restrict__ wr,
    const float* __restrict__ br, const float* __restrict__ w2,
    const float* __restrict__ b2, float* __restrict__ bfo,
    const float* __restrict__ W, _Float16* __restrict__ Wt)
{
    __shared__ __align__(16) char smem[18432];
    int tid = threadIdx.x;
    int blk = blockIdx.x;

    if (blk < 512) {
        // ---------------- basis functions -> bf (8 rows/block) ----------------
        float* c_l  = (float*)smem;             // 8*64  = 2 KB
        float* lr_l = (float*)(smem + 2048);    // 8*256 = 8 KB
        float* h_l  = (float*)(smem + 10240);   // 8*256 = 8 KB
        int b0 = blk * 8;

        for (int i = tid; i < 8 * 64; i += 256) c_l[i] = c[(size_t)b0 * 64 + i];

        // register-cache this thread's w1 column (64 coalesced loads, batched)
        float w1c[64];
#pragma unroll
        for (int u = 0; u < 64; ++u) w1c[u] = w1[u * 256 + tid];
        float b1s = b1[tid];
        __syncthreads();

        float h1[8];
#pragma unroll
        for (int r = 0; r < 8; ++r) h1[r] = b1s;
#pragma unroll
        for (int j4 = 0; j4 < 16; ++j4) {
#pragma unroll
            for (int r = 0; r < 8; ++r) {
                float4 cv = *(const float4*)&c_l[r * 64 + j4 * 4];
                h1[r] += cv.x * w1c[j4 * 4 + 0] + cv.y * w1c[j4 * 4 + 1] +
                         cv.z * w1c[j4 * 4 + 2] + cv.w * w1c[j4 * 4 + 3];
            }
        }
#pragma unroll
        for (int r = 0; r < 8; ++r) lr_l[r * 256 + tid] = LRELU(h1[r]);
        __syncthreads();

        float brv = br[tid];
        float h2[8];
#pragma unroll
        for (int r = 0; r < 8; ++r) h2[r] = h1[r] + brv;

        // wr loop in chunks of 32 rows: hoist 32 loads ahead of 256 FMAs
#pragma unroll 1
        for (int jc = 0; jc < 8; ++jc) {
            float w8[32];
#pragma unroll
            for (int u = 0; u < 32; ++u) w8[u] = wr[(jc * 32 + u) * 256 + tid];
#pragma unroll
            for (int j4 = 0; j4 < 8; ++j4) {
#pragma unroll
                for (int r = 0; r < 8; ++r) {
                    float4 lv = *(const float4*)&lr_l[r * 256 + jc * 32 + j4 * 4];
                    h2[r] += lv.x * w8[j4 * 4 + 0] + lv.y * w8[j4 * 4 + 1] +
                             lv.z * w8[j4 * 4 + 2] + lv.w * w8[j4 * 4 + 3];
                }
            }
        }
#pragma unroll
        for (int r = 0; r < 8; ++r) h_l[r * 256 + tid] = LRELU(h2[r]);
        __syncthreads();

        // bf[r][k]: 128 outputs, threads 0..127
        if (tid < 128) {
            int r = tid >> 4, k = tid & 15;
            float s = b2[k];
#pragma unroll 1
            for (int qc = 0; qc < 8; ++qc) {
                float wv[32];
#pragma unroll
                for (int u = 0; u < 32; ++u) wv[u] = w2[(qc * 32 + u) * 16 + k];
#pragma unroll
                for (int q4 = 0; q4 < 8; ++q4) {
                    float4 hv = *(const float4*)&h_l[r * 256 + qc * 32 + q4 * 4];
                    s += hv.x * wv[q4 * 4 + 0] + hv.y * wv[q4 * 4 + 1] +
                         hv.z * wv[q4 * 4 + 2] + hv.w * wv[q4 * 4 + 3];
                }
            }
            bfo[(size_t)(b0 + r) * 16 + k] = s;
        }

    } else if (blk < 1536) {
        // ---------------- W transpose + f16 convert ----------------
        float* t = (float*)smem;  // 64*65*4 = 16.25 KB
        int bid = blk - 512;
        int k  = bid >> 6;
        int it = (bid >> 3) & 7;
        int ot = bid & 7;
        int i0 = it * 64, o0 = ot * 64;

        int rr = tid >> 4, c4 = (tid & 15) * 4;
#pragma unroll
        for (int p = 0; p < 4; ++p) {
            int r = p * 16 + rr;
            float4 v = *(const float4*)&W[((size_t)(k * 512 + i0 + r)) * 512 + o0 + c4];
            t[r * 65 + c4 + 0] = v.x;
            t[r * 65 + c4 + 1] = v.y;
            t[r * 65 + c4 + 2] = v.z;
            t[r * 65 + c4 + 3] = v.w;
        }
        __syncthreads();

        int ol = tid >> 2, c0 = (tid & 3) * 16;
        _Float16 hb[16] __attribute__((aligned(16)));
#pragma unroll
        for (int u = 0; u < 16; ++u) hb[u] = (_Float16)t[(c0 + u) * 65 + ol];
        _Float16* dst = &Wt[(size_t)(o0 + ol) * 8192 + k * 512 + i0 + c0];
        *(float4*)dst       = *(const float4*)&hb[0];
        *(float4*)(dst + 8) = *(const float4*)&hb[8];

    } else {
        // ---------------- LayerNorm + LeakyReLU ----------------
        int lane = tid & 63;
        int row  = (blk - 1536) * 4 + (tid >> 6);
        const float* xr = x + (size_t)row * 512 + lane * 8;
        float4 v0 = *(const float4*)xr;
        float4 v1 = *(const float4*)(xr + 4);

        float s = v0.x + v0.y + v0.z + v0.w + v1.x + v1.y + v1.z + v1.w;
#pragma unroll
        for (int m = 1; m < 64; m <<= 1) s += __shfl_xor(s, m);
        float mean = s * (1.f / 512.f);

        float d, s2 = 0.f;
        d = v0.x - mean; s2 += d * d;
        d = v0.y - mean; s2 += d * d;
        d = v0.z - mean; s2 += d * d;
        d = v0.w - mean; s2 += d * d;
        d = v1.x - mean; s2 += d * d;
        d = v1.y - mean; s2 += d * d;
        d = v1.z - mean; s2 += d * d;
        d = v1.w - mean; s2 += d * d;
#pragma unroll
        for (int m = 1; m < 64; m <<= 1) s2 += __shfl_xor(s2, m);
        float rstd = rsqrtf(s2 * (1.f / 512.f) + 1e-5f);

        float4 g0 = *(const float4*)&gam[lane * 8];
        float4 g1 = *(const float4*)&gam[lane * 8 + 4];
        float4 b0 = *(const float4*)&bet[lane * 8];
        float4 b1v = *(const float4*)&bet[lane * 8 + 4];

        _Float16 o8[8] __attribute__((aligned(16)));
        float y;
        y = (v0.x - mean) * rstd * g0.x + b0.x;  y = LRELU(y); o8[0] = (_Float16)y;
        y = (v0.y - mean) * rstd * g0.y + b0.y;  y = LRELU(y); o8[1] = (_Float16)y;
        y = (v0.z - mean) * rstd * g0.z + b0.z;  y = LRELU(y); o8[2] = (_Float16)y;
        y = (v0.w - mean) * rstd * g0.w + b0.w;  y = LRELU(y); o8[3] = (_Float16)y;
        y = (v1.x - mean) * rstd * g1.x + b1v.x; y = LRELU(y); o8[4] = (_Float16)y;
        y = (v1.y - mean) * rstd * g1.y + b1v.y; y = LRELU(y); o8[5] = (_Float16)y;
        y = (v1.z - mean) * rstd * g1.z + b1v.z; y = LRELU(y); o8[6] = (_Float16)y;
        y = (v1.w - mean) * rstd * g1.w + b1v.w; y = LRELU(y); o8[7] = (_Float16)y;

        *(float4*)&a[(size_t)row * 512 + lane * 8] = *(const float4*)o8;
    }
}

// ---------------------------------------------------------------------------
// Main GEMM: partial[split][b,o] = sum_{kt in split} ((bf[:,kt]*a) @ W[kt])[b,o]
// BM=BN=256, BK=64, 8 waves (2M x 4N), 512 threads, 16x16x32 f16 MFMA.
// 2-deep tile double buffer; counted vmcnt(8) (never 0 in steady state);
// raw s_barrier (no __syncthreads -> no vmcnt(0) drain); T2 xor-swizzle:
// linear GL16 dest + inverse-swizzled global source + swizzled ds_read;
// T5 setprio around each 16-MFMA quadrant.   [UNCHANGED from round 6]
// ---------------------------------------------------------------------------
template <int NSPLIT>
__global__ __launch_bounds__(512, 2) void gemm_kernel(
    const _Float16* __restrict__ A,   // [4096][512]
    const _Float16* __restrict__ Wt,  // [512][8192]
    const float* __restrict__ bfg,    // [4096][16]
    float* __restrict__ pout)         // [NSPLIT][4096][512]
{
    constexpr int KTN = 16 / NSPLIT;   // kt-groups per block
    constexpr int NT  = KTN * 8;       // K-tiles of 64

    __shared__ _Float16 As[2][256 * 64];  // 64 KB
    __shared__ _Float16 Bs[2][256 * 64];  // 64 KB

    const int tid = threadIdx.x;
    const int bid = blockIdx.x;
    const int split = bid % NSPLIT;
    const int mn  = bid / NSPLIT;
    const int n0  = (mn & 1) * 256;
    const int bm0 = (mn >> 1) * 256;
    const int kt0 = split * KTN;

    const int lane = tid & 63, wid = tid >> 6;
    const int wm = wid >> 2, wn = wid & 3;   // 2 x 4 wave grid
    const int l16 = lane & 15, lg = lane >> 4;

    // per-lane A-row scales: row = bm0 + wm*128 + f*16 + l16
    _Float16 s16[KTN][8];
#pragma unroll
    for (int kt = 0; kt < KTN; ++kt)
#pragma unroll
        for (int f = 0; f < 8; ++f)
            s16[kt][f] = (_Float16)
                bfg[(size_t)(bm0 + wm * 128 + f * 16 + l16) * 16 + kt0 + kt];

    // ---- staging: tile = 256x64 f16 = 2048 16B-chunks; round p: chunk = p*512+tid
    // chunk -> (row = chunk>>3, c = chunk&7); source column chunk = c ^ (row&7)
    const int brow = tid >> 3;
    const int bc   = tid & 7;
    const int swc  = bc ^ (brow & 7);
    const _Float16* aAs = A  + (size_t)(bm0 + brow) * 512  + swc * 8;
    const _Float16* aBs = Wt + (size_t)(n0  + brow) * 8192 + swc * 8;

    auto STAGE = [&](int t, int buf) {
        const int ka = (t & 7) * 64;                            // A col offset
        const size_t kb = (size_t)(kt0 + (t >> 3)) * 512 + ka;  // B col offset
        char* la = (char*)&As[buf][0] + tid * 16;
        char* lb = (char*)&Bs[buf][0] + tid * 16;
#pragma unroll
        for (int p = 0; p < 4; ++p) {
            GL16(aAs + (size_t)(p * 64) * 512 + ka, la + p * 8192);
            GL16(aBs + (size_t)(p * 64) * 8192 + kb, lb + p * 8192);
        }
    };

    // ---- swizzled ds_read offsets
    const int swr = l16 & 7;
    const int aRowByte = (wm * 128 + l16) * 128;
    const int bRowByte = (wn * 64 + l16) * 128;
    const int sw0 = ((0 + lg) ^ swr) << 4;   // kk = 0
    const int sw1 = ((4 + lg) ^ swr) << 4;   // kk = 1

    const f32x4 z4 = {0.f, 0.f, 0.f, 0.f};
    f32x4 acc[8][4];
#pragma unroll
    for (int f = 0; f < 8; ++f)
#pragma unroll
        for (int nf = 0; nf < 4; ++nf) acc[f][nf] = z4;

    // ---- prologue: stage tiles 0,1; wait tile 0 (8 of 16 outstanding)
    STAGE(0, 0);
    STAGE(1, 1);
    asm volatile("s_waitcnt vmcnt(8)" ::: "memory");
    __builtin_amdgcn_s_barrier();
    __builtin_amdgcn_sched_barrier(0);

#pragma unroll
    for (int kt = 0; kt < KTN; ++kt) {
#pragma unroll 1
        for (int t2 = 0; t2 < 8; ++t2) {
            const int t = kt * 8 + t2;
            const int cur = t & 1;
            const char* Ab = (const char*)&As[cur][0];
            const char* Bb = (const char*)&Bs[cur][0];

            // B fragments for the whole K-tile (8 x ds_read_b128)
            f16x8 b8[4][2];
#pragma unroll
            for (int nf = 0; nf < 4; ++nf) {
                b8[nf][0] = *(const f16x8*)(Bb + bRowByte + nf * 2048 + sw0);
                b8[nf][1] = *(const f16x8*)(Bb + bRowByte + nf * 2048 + sw1);
            }

            // 4 quadrants: 4 A-reads + scale + 16 MFMA each
#pragma unroll
            for (int q = 0; q < 4; ++q) {
                f16x8 a0k0 = *(const f16x8*)(Ab + aRowByte + (2 * q + 0) * 2048 + sw0);
                f16x8 a0k1 = *(const f16x8*)(Ab + aRowByte + (2 * q + 0) * 2048 + sw1);
                f16x8 a1k0 = *(const f16x8*)(Ab + aRowByte + (2 * q + 1) * 2048 + sw0);
                f16x8 a1k1 = *(const f16x8*)(Ab + aRowByte + (2 * q + 1) * 2048 + sw1);
                const _Float16 sc0 = s16[kt][2 * q + 0];
                const _Float16 sc1 = s16[kt][2 * q + 1];
                a0k0 *= sc0; a0k1 *= sc0;
                a1k0 *= sc1; a1k1 *= sc1;
                __builtin_amdgcn_s_setprio(1);
#pragma unroll
                for (int nf = 0; nf < 4; ++nf) {
                    acc[2 * q + 0][nf] = MFMA16(a0k0, b8[nf][0], acc[2 * q + 0][nf]);
                    acc[2 * q + 0][nf] = MFMA16(a0k1, b8[nf][1], acc[2 * q + 0][nf]);
                    acc[2 * q + 1][nf] = MFMA16(a1k0, b8[nf][0], acc[2 * q + 1][nf]);
                    acc[2 * q + 1][nf] = MFMA16(a1k1, b8[nf][1], acc[2 * q + 1][nf]);
                }
                __builtin_amdgcn_s_setprio(0);
            }

            // barrier#1: all waves done reading buf[cur]
            __builtin_amdgcn_sched_barrier(0);
            __builtin_amdgcn_s_barrier();
            __builtin_amdgcn_sched_barrier(0);

            if (t + 2 < NT) {
                STAGE(t + 2, cur);                      // overwrite buf[cur]
                asm volatile("s_waitcnt vmcnt(8)" ::: "memory");  // tile t+1 landed
            } else {
                asm volatile("s_waitcnt vmcnt(0)" ::: "memory");
            }
            // barrier#2: buf[cur^1] (tile t+1) ready for every wave
            __builtin_amdgcn_s_barrier();
            __builtin_amdgcn_sched_barrier(0);
        }
    }

    // ---- epilogue: plain stores to this split's partial buffer
    float* op = pout + (size_t)split * (4096 * 512);
#pragma unroll
    for (int f = 0; f < 8; ++f)
#pragma unroll
        for (int j = 0; j < 4; ++j) {
            const int grow = bm0 + wm * 128 + f * 16 + lg * 4 + j;
            float* orow = op + (size_t)grow * 512 + n0 + wn * 64 + l16;
#pragma unroll
            for (int nf = 0; nf < 4; ++nf)
                orow[nf * 16] = acc[f][nf][j];
        }
}

// ---------------------------------------------------------------------------
// out = sum over splits of partials + bf @ bvec.  One float4 per thread.
// ---------------------------------------------------------------------------
__global__ __launch_bounds__(256) void reduce_kernel(const float* __restrict__ p,
                                                     const float* __restrict__ bfg,
                                                     const float* __restrict__ bvec,
                                                     float* __restrict__ out,
                                                     int nsplit)
{
    size_t i = (size_t)blockIdx.x * 256 + threadIdx.x;  // float4 index
    const float4* p4 = (const float4*)p;
    float4 s = p4[i];
    for (int sp = 1; sp < nsplit; ++sp) {
        float4 v = p4[i + (size_t)sp * 524288];
        s.x += v.x; s.y += v.y; s.z += v.z; s.w += v.w;
    }
    int b = (int)(i >> 7);        // 128 float4 per row
    int c = (int)(i & 127);
    const float* bfr = bfg + (size_t)b * 16;
    const float4* bv4 = (const float4*)bvec;  // [16][128] float4
#pragma unroll
    for (int k = 0; k < 16; ++k) {
        float bk = bfr[k];
        float4 v = bv4[k * 128 + c];
        s.x += bk * v.x; s.y += bk * v.y; s.z += bk * v.z; s.w += bk * v.w;
    }
    ((float4*)out)[i] = s;
}

// ---------------------------------------------------------------------------
extern "C" void kernel_launch(void* const* d_in, const int* in_sizes, int n_in,
                              void* d_out, int out_size, void* d_ws, size_t ws_size,
                              hipStream_t stream)
{
    const float* x    = (const float*)d_in[0];
    const float* c    = (const float*)d_in[1];
    const float* gam  = (const float*)d_in[2];
    const float* bet  = (const float*)d_in[3];
    const float* w1   = (const float*)d_in[4];
    const float* b1   = (const float*)d_in[5];
    const float* wr   = (const float*)d_in[6];
    const float* br   = (const float*)d_in[7];
    const float* w2   = (const float*)d_in[8];
    const float* b2   = (const float*)d_in[9];
    const float* W    = (const float*)d_in[10];
    const float* bvec = (const float*)d_in[11];
    float* out = (float*)d_out;

    const size_t outBytes  = (size_t)4096 * 512 * 4;                  // 8 MB
    const size_t miscBytes = (8u << 20) + (4u << 20) + (256u << 10);  // Wt+a+bf

    // nsplit=8 needs 76.25 MB of ws (selected successfully rounds 4-6).
    int nsplit = (ws_size >= 8 * outBytes + miscBytes) ? 8 : 4;

    char* ws = (char*)d_ws;
    size_t pbytes = (size_t)nsplit * outBytes;
    float*    part = (float*)ws;
    _Float16* Wt   = (_Float16*)(ws + pbytes);
    _Float16* af   = (_Float16*)(ws + pbytes + (8u << 20));
    float*    bf   = (float*)(ws + pbytes + (12u << 20));

    prep_kernel<<<dim3(2560), dim3(256), 0, stream>>>(
        x, gam, bet, af, c, w1, b1, wr, br, w2, b2, bf, W, Wt);

    if (nsplit == 8) {
        // 16 m-tiles * 2 n-tiles * 8 splits = 256 blocks (1 per CU)
        gemm_kernel<8><<<dim3(256), dim3(512), 0, stream>>>(af, Wt, bf, part);
    } else {
        gemm_kernel<4><<<dim3(128), dim3(512), 0, stream>>>(af, Wt, bf, part);
    }
    reduce_kernel<<<dim3(2048), dim3(256), 0, stream>>>(part, bf, bvec, out, nsplit);
}